// Round 5
// baseline (429.475 us; speedup 1.0000x reference)
//
#include <hip/hip_runtime.h>
#include <hip/hip_bf16.h>
#include <stdint.h>

#define BATCH 8192
#define INF   1024
#define GN    1024
#define GK    8192   // 8 degrees (d=1..8) * 1024; d=0 handled as f32 bias

#define BM 256
#define BN 128
#define BK 64
#define NT (GK / BK)          // 128 K-tiles
#define ABYTES (BM * BK * 2)  // 32768 per A buffer
#define SMEM_BYTES (3 * ABYTES)   // 96 KiB: A-only triple buffer (B lives in regs)

typedef __attribute__((ext_vector_type(4))) float floatx4;
typedef __attribute__((ext_vector_type(8))) short short8;

static __device__ __forceinline__ ushort f2bf(float f) {
  union { float f; uint32_t u; } v; v.f = f;
  uint32_t r = v.u + 0x7FFF + ((v.u >> 16) & 1);   // RNE
  return (ushort)(r >> 16);
}

// ---------------------------------------------------------------------------
// Repack coef (I,O,9) f32 -> Wt bf16 [O][K], k=(d-1)*1024+i; fold d=0 bias.
__global__ __launch_bounds__(256) void repack(const float* __restrict__ coef,
                                              ushort* __restrict__ Wt,
                                              float* __restrict__ bias) {
  __shared__ ushort lds[32 * 9 * 33];
  __shared__ float  bl[32 * 33];
  const int i0 = (blockIdx.x >> 5) << 5;
  const int o0 = (blockIdx.x & 31) << 5;
  const int t = threadIdx.x;
  for (int idx = t; idx < 32 * 288; idx += 256) {
    const int ii  = idx / 288;
    const int rem = idx - ii * 288;          // oo*9 + d
    const float f = coef[(size_t)(i0 + ii) * 9216 + (size_t)o0 * 9 + rem];
    lds[rem * 33 + ii] = f2bf(f);
    const int oo = rem / 9;
    if (rem == oo * 9) bl[oo * 33 + ii] = f;
  }
  __syncthreads();
  if (t < 32) {
    float s = 0.f;
    #pragma unroll
    for (int ii = 0; ii < 32; ++ii) s += bl[t * 33 + ii];
    atomicAdd(&bias[o0 + t], s);
  }
  for (int idx = t; idx < 32 * 8 * 32; idx += 256) {
    const int oo  = idx >> 8;
    const int rem = idx & 255;
    const int d1  = rem >> 5;
    const int ii  = rem & 31;
    Wt[(size_t)(o0 + oo) * GK + (size_t)d1 * 1024 + (i0 + ii)] =
        lds[(oo * 9 + d1 + 1) * 33 + ii];
  }
}

// ---------------------------------------------------------------------------
// Featurize: 8 i's per thread, 16B stores.
__global__ __launch_bounds__(256) void featurize(const float* __restrict__ x,
                                                 ushort* __restrict__ Cf) {
  const int tid = blockIdx.x * 256 + threadIdx.x;
  const int b = tid >> 7;                    // 128 threads per row
  const int i = (tid & 127) << 3;
  const float* xp = x + (size_t)b * INF + i;
  const float4 v0 = *reinterpret_cast<const float4*>(xp);
  const float4 v1 = *reinterpret_cast<const float4*>(xp + 4);
  float tt[8] = {tanhf(v0.x), tanhf(v0.y), tanhf(v0.z), tanhf(v0.w),
                 tanhf(v1.x), tanhf(v1.y), tanhf(v1.z), tanhf(v1.w)};
  float Tp[8], Tc[8];
  #pragma unroll
  for (int j = 0; j < 8; ++j) { Tp[j] = 1.f; Tc[j] = tt[j]; }
  ushort* base = Cf + (size_t)b * GK + i;
  #pragma unroll
  for (int d = 1; d <= 8; ++d) {
    short8 u;
    #pragma unroll
    for (int j = 0; j < 8; ++j) u[j] = (short)f2bf(Tc[j]);
    *reinterpret_cast<short8*>(base + (size_t)(d - 1) * 1024) = u;
    #pragma unroll
    for (int j = 0; j < 8; ++j) {
      const float Tn = 2.f * tt[j] * Tc[j] - Tp[j];
      Tp[j] = Tc[j]; Tc[j] = Tn;
    }
  }
}

// ---------------------------------------------------------------------------
// bf16 GEMM, 4-phase counted-vmcnt schedule. BM=256 BN=128 BK=64, 512 thr
// (8 waves, 4M x 2N, 64x64 each). A: gload_lds triple-buffer (96 KiB LDS,
// XOR-swizzled via pre-swizzled source). B: global->VGPR, double-buffered in
// registers one tile ahead (16 KiB B-slice is L1-resident; 4 M-waves share).
// vmcnt ledger (A=4 issues/tile, B=8 reg-loads/tile, order B8 then A4):
// main p3 waits A4(t+1) -> vmcnt(12)=B8(t+1)+A4(t+2); peel: 8 then 0.

__device__ __forceinline__ void gload16(const char* src, char* dstp) {
  __builtin_amdgcn_global_load_lds(
      (const __attribute__((address_space(1))) void*)src,
      (__attribute__((address_space(3))) void*)dstp, 16, 0, 0);
}

template<int CB, bool DOSTAGE, bool PFB, int VMN>
__device__ __forceinline__ void tile_step(char* smem, int kt,
    const char* const* gA, const char* const* gBf, int dst,
    int wm0, int lr, int lk,
    short8 (&bfu)[4][2], short8 (&bff)[4][2], floatx4 (&acc)[4][4]) {
  constexpr int NB = (CB + 2) % 3;
  const char* Ab = smem + CB * ABYTES;
  const int xm = lr & 7;
  const size_t kb = (size_t)(kt + 2) * 128;      // A staged tile byte offset
  short8 af[4][2];

#define QUAD(MI0, NI0)                                                         \
  __builtin_amdgcn_s_setprio(1);                                               \
  _Pragma("unroll") for (int kk = 0; kk < 2; ++kk)                             \
    _Pragma("unroll") for (int mi = MI0; mi < MI0 + 2; ++mi)                   \
      _Pragma("unroll") for (int ni = NI0; ni < NI0 + 2; ++ni)                 \
        acc[mi][ni] = __builtin_amdgcn_mfma_f32_16x16x32_bf16(                 \
            af[mi][kk], bfu[ni][kk], acc[mi][ni], 0, 0, 0);                    \
  __builtin_amdgcn_s_setprio(0);

  // ---- phase 0: B(t+1) reg-prefetch; af[0..1]; stage A slabs 0,1; QUAD(0,0)
  if (PFB) {
    const size_t koff = (size_t)(kt + 1) * 128;
    #pragma unroll
    for (int ni = 0; ni < 4; ++ni)
      #pragma unroll
      for (int kk = 0; kk < 2; ++kk)
        bff[ni][kk] = *reinterpret_cast<const short8*>(gBf[ni] + koff + kk * 64);
  }
  #pragma unroll
  for (int mi = 0; mi < 2; ++mi)
    #pragma unroll
    for (int kk = 0; kk < 2; ++kk)
      af[mi][kk] = *reinterpret_cast<const short8*>(
          Ab + (wm0 + mi * 16 + lr) * 128 + ((((kk << 2) | lk) ^ xm) << 4));
  if (DOSTAGE) {
    gload16(gA[0] + kb, smem + NB * ABYTES + 0 * 8192 + dst);
    gload16(gA[1] + kb, smem + NB * ABYTES + 1 * 8192 + dst);
  }
  __builtin_amdgcn_s_barrier();
  __builtin_amdgcn_sched_barrier(0);
  QUAD(0, 0)

  // ---- phase 1: af[2..3]; stage A slabs 2,3; QUAD(0,2)
  #pragma unroll
  for (int mi = 2; mi < 4; ++mi)
    #pragma unroll
    for (int kk = 0; kk < 2; ++kk)
      af[mi][kk] = *reinterpret_cast<const short8*>(
          Ab + (wm0 + mi * 16 + lr) * 128 + ((((kk << 2) | lk) ^ xm) << 4));
  if (DOSTAGE) {
    gload16(gA[2] + kb, smem + NB * ABYTES + 2 * 8192 + dst);
    gload16(gA[3] + kb, smem + NB * ABYTES + 3 * 8192 + dst);
  }
  __builtin_amdgcn_s_barrier();
  __builtin_amdgcn_sched_barrier(0);
  QUAD(0, 2)

  // ---- phase 2: QUAD(2,0)
  __builtin_amdgcn_s_barrier();
  __builtin_amdgcn_sched_barrier(0);
  QUAD(2, 0)

  // ---- phase 3: counted vmcnt certifies A(t+1) LDS-resident; QUAD(2,2)
  if constexpr (VMN == 12) asm volatile("s_waitcnt vmcnt(12)" ::: "memory");
  else if constexpr (VMN == 8) asm volatile("s_waitcnt vmcnt(8)" ::: "memory");
  else asm volatile("s_waitcnt vmcnt(0)" ::: "memory");
  __builtin_amdgcn_s_barrier();
  __builtin_amdgcn_sched_barrier(0);
  QUAD(2, 2)
#undef QUAD
}

__global__ __launch_bounds__(512, 2) void gemm_bt(const ushort* __restrict__ A,
                                                  const ushort* __restrict__ Bt,
                                                  const float* __restrict__ bias,
                                                  float* __restrict__ C) {
  extern __shared__ __align__(16) char smem[];
  const int t = threadIdx.x;
  // bijective XCD swizzle: 256 blocks -> 32 contiguous per XCD
  const int bid = (blockIdx.x & 7) * 32 + (blockIdx.x >> 3);
  const int bm0 = (bid >> 3) << 8;
  const int bn0 = (bid & 7) << 7;
  const int lane = t & 63;
  const int wid  = t >> 6;
  const int wm0 = (wid >> 1) << 6;
  const int wn0 = (wid & 1) << 6;
  const int lr = lane & 15;
  const int lk = lane >> 4;

  // A staging source: row = t>>3 within 64-row slab, chunk pre-XOR'd
  const int srow = t >> 3;
  const int schunk = ((t & 7) ^ (srow & 7)) << 4;
  const char* gA[4];
  #pragma unroll
  for (int j = 0; j < 4; ++j)
    gA[j] = (const char*)(A + (size_t)(bm0 + j * 64 + srow) * GK) + schunk;
  const int dst = t << 4;

  // B fragment base addrs: row = bn0+wn0+ni*16+lr, k-chunk base = lk*16 bytes
  const char* gBf[4];
  #pragma unroll
  for (int ni = 0; ni < 4; ++ni)
    gBf[ni] = (const char*)(Bt + (size_t)(bn0 + wn0 + ni * 16 + lr) * GK) + lk * 16;

  floatx4 acc[4][4] = {};
  short8 bf0[4][2], bf1[4][2];

  // prologue: stage A(0)->buf0, A(1)->buf1; B(0)->bf0; drain A(0): vmcnt(12)
  #pragma unroll
  for (int j = 0; j < 4; ++j) gload16(gA[j], smem + j * 8192 + dst);
  #pragma unroll
  for (int j = 0; j < 4; ++j) gload16(gA[j] + 128, smem + ABYTES + j * 8192 + dst);
  #pragma unroll
  for (int ni = 0; ni < 4; ++ni)
    #pragma unroll
    for (int kk = 0; kk < 2; ++kk)
      bf0[ni][kk] = *reinterpret_cast<const short8*>(gBf[ni] + kk * 64);
  asm volatile("s_waitcnt vmcnt(12)" ::: "memory");
  __builtin_amdgcn_s_barrier();
  __builtin_amdgcn_sched_barrier(0);

  // main loop: tiles 0..125, unrolled by 6 (LCM of buf-rotation 3, B-parity 2)
  for (int kt = 0; kt < NT - 2; kt += 6) {
    tile_step<0, true, true, 12>(smem, kt,     gA, gBf, dst, wm0, lr, lk, bf0, bf1, acc);
    tile_step<1, true, true, 12>(smem, kt + 1, gA, gBf, dst, wm0, lr, lk, bf1, bf0, acc);
    tile_step<2, true, true, 12>(smem, kt + 2, gA, gBf, dst, wm0, lr, lk, bf0, bf1, acc);
    tile_step<0, true, true, 12>(smem, kt + 3, gA, gBf, dst, wm0, lr, lk, bf1, bf0, acc);
    tile_step<1, true, true, 12>(smem, kt + 4, gA, gBf, dst, wm0, lr, lk, bf0, bf1, acc);
    tile_step<2, true, true, 12>(smem, kt + 5, gA, gBf, dst, wm0, lr, lk, bf1, bf0, acc);
  }
  // peel tiles 126 (prefetch B(127), no A-stage) and 127 (nothing)
  tile_step<0, false, true, 8>(smem, 126, gA, gBf, dst, wm0, lr, lk, bf0, bf1, acc);
  tile_step<1, false, false, 0>(smem, 127, gA, gBf, dst, wm0, lr, lk, bf1, bf0, acc);

  // epilogue: C[row][col] = acc + bias[col]; D layout col=lane&15, row=lk*4+r
  #pragma unroll
  for (int ni = 0; ni < 4; ++ni) {
    const int col = bn0 + wn0 + ni * 16 + lr;
    const float bv = bias[col];
    #pragma unroll
    for (int mi = 0; mi < 4; ++mi) {
      const int row = bm0 + wm0 + mi * 16 + lk * 4;
      #pragma unroll
      for (int r = 0; r < 4; ++r)
        C[(size_t)(row + r) * GN + col] = acc[mi][ni][r] + bv;
    }
  }
}

// ---------------------------------------------------------------------------
extern "C" void kernel_launch(void* const* d_in, const int* in_sizes, int n_in,
                              void* d_out, int out_size, void* d_ws, size_t ws_size,
                              hipStream_t stream) {
  const float* x    = (const float*)d_in[0];
  const float* coef = (const float*)d_in[1];
  float* out = (float*)d_out;

  char* ws = (char*)d_ws;
  ushort* Cf   = (ushort*)ws;                                   // 128 MiB
  ushort* Wt   = (ushort*)(ws + (size_t)BATCH * GK * 2);        //  16 MiB
  float*  bias = (float*)(ws + (size_t)BATCH * GK * 2 + (size_t)GN * GK * 2);

  hipFuncSetAttribute(reinterpret_cast<const void*>(&gemm_bt),
                      hipFuncAttributeMaxDynamicSharedMemorySize, SMEM_BYTES);

  hipMemsetAsync(bias, 0, GN * sizeof(float), stream);
  repack<<<1024, 256, 0, stream>>>(coef, Wt, bias);
  featurize<<<(BATCH * INF / 8) / 256, 256, 0, stream>>>(x, Cf);
  gemm_bt<<<256, 512, SMEM_BYTES, stream>>>(Cf, Wt, bias, out);
}

// Round 6
// 314.436 us; speedup vs baseline: 1.3659x; 1.3659x over previous
//
#include <hip/hip_runtime.h>
#include <hip/hip_bf16.h>
#include <stdint.h>

#define BATCH 8192
#define INF   1024
#define GN    1024
#define GK    8192   // 8 degrees (d=1..8) * 1024; d=0 handled as f32 bias

// GEMM geometry: split-K=2, BM=BN=256, BK=32, 8 waves (2M x 4N) of 128x64.
#define BM 256
#define BN 256
#define BK 32
#define KHALF 4096
#define NT (KHALF / BK)        // 128 tiles per block
#define BUFSZ 32768            // A 16KB + B 16KB per K-tile
#define SMEM_BYTES (4 * BUFSZ) // 128 KiB, 4-deep rotation

typedef __attribute__((ext_vector_type(4))) float floatx4;
typedef __attribute__((ext_vector_type(8))) short short8;

static __device__ __forceinline__ ushort f2bf(float f) {
  union { float f; uint32_t u; } v; v.f = f;
  uint32_t r = v.u + 0x7FFF + ((v.u >> 16) & 1);   // RNE
  return (ushort)(r >> 16);
}

// ---------------------------------------------------------------------------
// Repack coef (I,O,9) f32 -> Wt bf16 [O][K], k=(d-1)*1024+i; fold d=0 bias.
__global__ __launch_bounds__(256) void repack(const float* __restrict__ coef,
                                              ushort* __restrict__ Wt,
                                              float* __restrict__ bias) {
  __shared__ ushort lds[32 * 9 * 33];
  __shared__ float  bl[32 * 33];
  const int i0 = (blockIdx.x >> 5) << 5;
  const int o0 = (blockIdx.x & 31) << 5;
  const int t = threadIdx.x;
  for (int idx = t; idx < 32 * 288; idx += 256) {
    const int ii  = idx / 288;
    const int rem = idx - ii * 288;          // oo*9 + d
    const float f = coef[(size_t)(i0 + ii) * 9216 + (size_t)o0 * 9 + rem];
    lds[rem * 33 + ii] = f2bf(f);
    const int oo = rem / 9;
    if (rem == oo * 9) bl[oo * 33 + ii] = f;
  }
  __syncthreads();
  if (t < 32) {
    float s = 0.f;
    #pragma unroll
    for (int ii = 0; ii < 32; ++ii) s += bl[t * 33 + ii];
    atomicAdd(&bias[o0 + t], s);
  }
  for (int idx = t; idx < 32 * 8 * 32; idx += 256) {
    const int oo  = idx >> 8;
    const int rem = idx & 255;
    const int d1  = rem >> 5;
    const int ii  = rem & 31;
    Wt[(size_t)(o0 + oo) * GK + (size_t)d1 * 1024 + (i0 + ii)] =
        lds[(oo * 9 + d1 + 1) * 33 + ii];
  }
}

// ---------------------------------------------------------------------------
__global__ __launch_bounds__(256) void featurize(const float* __restrict__ x,
                                                 ushort* __restrict__ Cf) {
  const int tid = blockIdx.x * 256 + threadIdx.x;
  const int b = tid >> 7;
  const int i = (tid & 127) << 3;
  const float* xp = x + (size_t)b * INF + i;
  const float4 v0 = *reinterpret_cast<const float4*>(xp);
  const float4 v1 = *reinterpret_cast<const float4*>(xp + 4);
  float tt[8] = {tanhf(v0.x), tanhf(v0.y), tanhf(v0.z), tanhf(v0.w),
                 tanhf(v1.x), tanhf(v1.y), tanhf(v1.z), tanhf(v1.w)};
  float Tp[8], Tc[8];
  #pragma unroll
  for (int j = 0; j < 8; ++j) { Tp[j] = 1.f; Tc[j] = tt[j]; }
  ushort* base = Cf + (size_t)b * GK + i;
  #pragma unroll
  for (int d = 1; d <= 8; ++d) {
    short8 u;
    #pragma unroll
    for (int j = 0; j < 8; ++j) u[j] = (short)f2bf(Tc[j]);
    *reinterpret_cast<short8*>(base + (size_t)(d - 1) * 1024) = u;
    #pragma unroll
    for (int j = 0; j < 8; ++j) {
      const float Tn = 2.f * tt[j] * Tc[j] - Tp[j];
      Tp[j] = Tc[j]; Tc[j] = Tn;
    }
  }
}

// ---------------------------------------------------------------------------
// Split-K bf16 GEMM. Block = (m, n, s): C_part[s][m-tile][n-tile], K-half s.
// 8 waves (2M x 4N), per-wave 128x64 = 8mi x 4ni frags of 16x16x32, BK=32.
// 4-buffer LDS rotation: tile t computes buf[t&3], stages t+3 (2 A + 2 B
// gload_lds issues), end-of-tile vmcnt(8) drains t+1's 4 issues.
// 64B rows, XOR swizzle key(r) = (r ^ (r>>2)) & 3 on 16B chunks: 2-way (free)
// on ds_read_b128; applied via pre-swizzled global source (linear LDS dest).

__device__ __forceinline__ void gload16(const char* src, char* dstp) {
  __builtin_amdgcn_global_load_lds(
      (const __attribute__((address_space(1))) void*)src,
      (__attribute__((address_space(3))) void*)dstp, 16, 0, 0);
}

template<int CB, bool DOSTAGE, int VMN>
__device__ __forceinline__ void tile_step(char* smem, int kt,
    const char* const* gAs, const char* const* gBs, int dst,
    int wm0, int wn0, int lr, int rc, floatx4 (&acc)[8][4]) {
  constexpr int NB = (CB + 3) & 3;
  const char* Ab = smem + CB * BUFSZ;
  const char* Bb = smem + CB * BUFSZ + 16384;
  const size_t kb = (size_t)(kt + 3) * 64;       // staged tile k byte offset
  short8 af[8], bf[4];

#define QUAD(MI0)                                                              \
  __builtin_amdgcn_s_setprio(1);                                               \
  _Pragma("unroll") for (int mi = MI0; mi < MI0 + 4; ++mi)                     \
    _Pragma("unroll") for (int ni = 0; ni < 4; ++ni)                           \
      acc[mi][ni] = __builtin_amdgcn_mfma_f32_16x16x32_bf16(                   \
          af[mi], bf[ni], acc[mi][ni], 0, 0, 0);                               \
  __builtin_amdgcn_s_setprio(0);

  // ---- phase 0: bf[0..3] + af[0..3]; stage A(t+3); QUAD(mi 0..3)
  #pragma unroll
  for (int ni = 0; ni < 4; ++ni)
    bf[ni] = *reinterpret_cast<const short8*>(Bb + (wn0 + ni * 16 + lr) * 64 + rc);
  #pragma unroll
  for (int mi = 0; mi < 4; ++mi)
    af[mi] = *reinterpret_cast<const short8*>(Ab + (wm0 + mi * 16 + lr) * 64 + rc);
  if (DOSTAGE) {
    gload16(gAs[0] + kb, smem + NB * BUFSZ + 0 * 8192 + dst);
    gload16(gAs[1] + kb, smem + NB * BUFSZ + 1 * 8192 + dst);
  }
  __builtin_amdgcn_s_barrier();
  __builtin_amdgcn_sched_barrier(0);
  QUAD(0)

  // ---- phase 1: af[4..7]; stage B(t+3); QUAD(mi 4..7); certify t+1
  #pragma unroll
  for (int mi = 4; mi < 8; ++mi)
    af[mi] = *reinterpret_cast<const short8*>(Ab + (wm0 + mi * 16 + lr) * 64 + rc);
  if (DOSTAGE) {
    gload16(gBs[0] + kb, smem + NB * BUFSZ + 16384 + 0 * 8192 + dst);
    gload16(gBs[1] + kb, smem + NB * BUFSZ + 16384 + 1 * 8192 + dst);
  }
  if constexpr (VMN == 8) asm volatile("s_waitcnt vmcnt(8)" ::: "memory");
  else if constexpr (VMN == 4) asm volatile("s_waitcnt vmcnt(4)" ::: "memory");
  else if constexpr (VMN == 0) asm volatile("s_waitcnt vmcnt(0)" ::: "memory");
  __builtin_amdgcn_s_barrier();
  __builtin_amdgcn_sched_barrier(0);
  QUAD(4)
#undef QUAD
}

__global__ __launch_bounds__(512, 2) void gemm_bt(const ushort* __restrict__ A,
                                                  const ushort* __restrict__ Bt,
                                                  float* __restrict__ out,
                                                  float* __restrict__ part1) {
  extern __shared__ __align__(16) char smem[];
  const int t = threadIdx.x;
  // XCD swizzle: XCD x owns bids [32x, 32x+32) = one (n, s) pair, 32 m-tiles.
  // Wt panel per (n, s) = 256 rows x 4096 k x 2B = 2 MB -> XCD-L2-resident.
  const int bid = (blockIdx.x & 7) * 32 + (blockIdx.x >> 3);
  const int chunk = bid >> 5;                    // 0..7
  const int n = chunk >> 1;                      // 0..3
  const int s = chunk & 1;                       // K-half
  const int m = bid & 31;                        // 0..31
  const int bm0 = m << 8;
  const int bn0 = n << 8;
  const int lane = t & 63;
  const int wid  = t >> 6;
  const int wm0 = (wid >> 2) << 7;               // 0 or 128
  const int wn0 = (wid & 3) << 6;                // 0,64,128,192
  const int lr = lane & 15;
  const int lk = lane >> 4;
  // reader swizzled chunk offset: key(lr) = (lr ^ (lr>>2)) & 3
  const int rc = ((lk ^ ((lr ^ (lr >> 2)) & 3)) << 4);

  // staging: thread t -> row (t>>2) within 128-row slab, chunk (t&3); source
  // chunk pre-XOR'd with skey = ((t>>2) ^ (t>>4)) & 3 (j*128 rows keep key).
  const int srow = t >> 2;
  const int schunk = (((t & 3) ^ ((srow ^ (srow >> 2)) & 3)) << 4);
  const size_t khalf_b = (size_t)s * KHALF * 2;  // k-half byte offset in row
  const char* gAs[2]; const char* gBs[2];
  #pragma unroll
  for (int j = 0; j < 2; ++j) {
    gAs[j] = (const char*)(A  + (size_t)(bm0 + j * 128 + srow) * GK) + khalf_b + schunk;
    gBs[j] = (const char*)(Bt + (size_t)(bn0 + j * 128 + srow) * GK) + khalf_b + schunk;
  }
  const int dst = t << 4;

  floatx4 acc[8][4] = {};

  // prologue: stage tiles 0,1,2 (12 issues); drain tile 0 -> vmcnt(8)
  #pragma unroll
  for (int pt = 0; pt < 3; ++pt) {
    #pragma unroll
    for (int j = 0; j < 2; ++j) {
      gload16(gAs[j] + pt * 64, smem + pt * BUFSZ + j * 8192 + dst);
      gload16(gBs[j] + pt * 64, smem + pt * BUFSZ + 16384 + j * 8192 + dst);
    }
  }
  asm volatile("s_waitcnt vmcnt(8)" ::: "memory");
  __builtin_amdgcn_s_barrier();
  __builtin_amdgcn_sched_barrier(0);

  // main: tiles 0..123 (stage t+3, vmcnt(8)); peel 124(st,8) 125(4) 126(0) 127
  for (int kt = 0; kt < NT - 4; kt += 4) {
    tile_step<0, true, 8>(smem, kt,     gAs, gBs, dst, wm0, wn0, lr, rc, acc);
    tile_step<1, true, 8>(smem, kt + 1, gAs, gBs, dst, wm0, wn0, lr, rc, acc);
    tile_step<2, true, 8>(smem, kt + 2, gAs, gBs, dst, wm0, wn0, lr, rc, acc);
    tile_step<3, true, 8>(smem, kt + 3, gAs, gBs, dst, wm0, wn0, lr, rc, acc);
  }
  tile_step<0, true,  8>(smem, NT - 4, gAs, gBs, dst, wm0, wn0, lr, rc, acc);
  tile_step<1, false, 4>(smem, NT - 3, gAs, gBs, dst, wm0, wn0, lr, rc, acc);
  tile_step<2, false, 0>(smem, NT - 2, gAs, gBs, dst, wm0, wn0, lr, rc, acc);
  tile_step<3, false, -1>(smem, NT - 1, gAs, gBs, dst, wm0, wn0, lr, rc, acc);

  // epilogue: partial write (bias added in reduce). D layout col=lr, row=lk*4+r
  float* P = s ? part1 : out;
  #pragma unroll
  for (int ni = 0; ni < 4; ++ni) {
    const int col = bn0 + wn0 + ni * 16 + lr;
    #pragma unroll
    for (int mi = 0; mi < 8; ++mi) {
      const int row = bm0 + wm0 + mi * 16 + lk * 4;
      #pragma unroll
      for (int r = 0; r < 4; ++r)
        P[(size_t)(row + r) * GN + col] = acc[mi][ni][r];
    }
  }
}

// ---------------------------------------------------------------------------
// out = out(part0) + part1 + bias ; float4 grid-stride.
__global__ __launch_bounds__(256) void reduce_add(float* __restrict__ out,
                                                  const float* __restrict__ p1,
                                                  const float* __restrict__ bias) {
  const int total4 = BATCH * GN / 4;             // 2,097,152
  for (int i = blockIdx.x * 256 + threadIdx.x; i < total4; i += 2048 * 256) {
    float4 o = reinterpret_cast<float4*>(out)[i];
    const float4 q = reinterpret_cast<const float4*>(p1)[i];
    const float4 b = reinterpret_cast<const float4*>(bias)[i & 255];
    o.x += q.x + b.x; o.y += q.y + b.y; o.z += q.z + b.z; o.w += q.w + b.w;
    reinterpret_cast<float4*>(out)[i] = o;
  }
}

// ---------------------------------------------------------------------------
extern "C" void kernel_launch(void* const* d_in, const int* in_sizes, int n_in,
                              void* d_out, int out_size, void* d_ws, size_t ws_size,
                              hipStream_t stream) {
  const float* x    = (const float*)d_in[0];
  const float* coef = (const float*)d_in[1];
  float* out = (float*)d_out;

  char* ws = (char*)d_ws;
  ushort* Cf   = (ushort*)ws;                                        // 128 MiB
  ushort* Wt   = (ushort*)(ws + (size_t)BATCH * GK * 2);             //  16 MiB
  float*  part1= (float*)(ws + (size_t)BATCH * GK * 2 + (size_t)GN * GK * 2);  // 33.5 MiB
  float*  bias = part1 + (size_t)BATCH * GN;

  hipFuncSetAttribute(reinterpret_cast<const void*>(&gemm_bt),
                      hipFuncAttributeMaxDynamicSharedMemorySize, SMEM_BYTES);

  hipMemsetAsync(bias, 0, GN * sizeof(float), stream);
  repack<<<1024, 256, 0, stream>>>(coef, Wt, bias);
  featurize<<<(BATCH * INF / 8) / 256, 256, 0, stream>>>(x, Cf);
  gemm_bt<<<256, 512, SMEM_BYTES, stream>>>(Cf, Wt, out, part1);
  reduce_add<<<2048, 256, 0, stream>>>(out, part1, bias);
}